// Round 8
// baseline (2347.773 us; speedup 1.0000x reference)
//
#include <hip/hip_runtime.h>
#include <hip/hip_bf16.h>

// GCN: h1 = relu(Dinv (A+I) Dinv (x W1) + b1); h2 = relu(same with W2);
// out = mean-pool-by-graph(h2) @ Wl + bl.
// Identity: hs[u] = (xW)[u]*dinv[u]; conv[v] = dinv[v]*(hs[v] + sum_in hs[u]) + b.
// R8: conv rebuilt as block-per-bucket LDS-accumulate. R7's wave-per-node
// gather was 57% VALU-issue (23 wave-instr/edge: epilogue shfl reductions,
// broadcasts, exec juggling). Now 8-lane teams stream bucket edges, unpack,
// ds_add_f32 into a stride-65 LDS accumulator; csr is never built (bfill ->
// tiny k_hist for dinv). NB=512 -> 2 blocks/CU exactly, 54KB LDS, full occ.

#define HDIM 64
#define NB 512      // dst-range buckets
#define SGRID 256   // blocks for bcount/bscatter
#define MAXNPB 208  // max nodes per bucket (N <= 106496); N <= 131072 for 17-bit src

static __device__ __forceinline__ unsigned bf16_bits(float f) {  // RNE
    unsigned u = __float_as_uint(f);
    return (u + 0x7fff + ((u >> 16) & 1)) >> 16;
}
static __device__ __forceinline__ float bflo(unsigned w) { return __uint_as_float(w << 16); }
static __device__ __forceinline__ float bfhi(unsigned w) { return __uint_as_float(w & 0xffff0000u); }
static __device__ __forceinline__ float rdlane(float v, int l) {
    return __uint_as_float(__builtin_amdgcn_readlane(__float_as_uint(v), l));
}

__global__ __launch_bounds__(1024) void k_bcount(const int* __restrict__ dst,
        int* __restrict__ blkhist, int E, int npb, int chunk) {
    __shared__ int lh[NB];
    int tid = threadIdx.x;
    for (int i = tid; i < NB; i += 1024) lh[i] = 0;
    __syncthreads();
    int e0 = blockIdx.x * chunk, e1 = min(E, e0 + chunk);
    for (int e = e0 + tid; e < e1; e += 1024)
        atomicAdd(&lh[(unsigned)dst[e] / (unsigned)npb], 1);
    __syncthreads();
    for (int i = tid; i < NB; i += 1024) blkhist[blockIdx.x * NB + i] = lh[i];
}

// One block per bucket b: exclusive scan of blkhist[*][b] over blocks (in place),
// total -> bcnt[b].
__global__ void k_bscan2(int* __restrict__ blkhist, int* __restrict__ bcnt) {
    __shared__ int s[SGRID];
    int b = blockIdx.x, t = threadIdx.x;
    int orig = blkhist[t * NB + b];
    s[t] = orig;
    __syncthreads();
    for (int off = 1; off < SGRID; off <<= 1) {
        int v = 0;
        if (t >= off) v = s[t - off];
        __syncthreads();
        s[t] += v;
        __syncthreads();
    }
    blkhist[t * NB + b] = s[t] - orig;        // exclusive prefix
    if (t == SGRID - 1) bcnt[b] = s[t];
}

__global__ void k_bscan(const int* __restrict__ bcnt, int* __restrict__ bstart) {
    if (threadIdx.x == 0) {
        int s = 0;
        for (int i = 0; i < NB; ++i) { bstart[i] = s; s += bcnt[i]; }
        bstart[NB] = s;
    }
}

__global__ __launch_bounds__(1024) void k_bscatter(const int* __restrict__ src,
        const int* __restrict__ dst, const int* __restrict__ bstart,
        const int* __restrict__ blkhist, unsigned* __restrict__ ebuf,
        int E, int npb, int chunk) {
    __shared__ int base[NB], lcur[NB];
    int tid = threadIdx.x;
    for (int i = tid; i < NB; i += 1024) {
        base[i] = bstart[i] + blkhist[blockIdx.x * NB + i];
        lcur[i] = 0;
    }
    __syncthreads();
    int e0 = blockIdx.x * chunk, e1 = min(E, e0 + chunk);
    for (int e = e0 + tid; e < e1; e += 1024) {
        int d = dst[e];
        unsigned b = (unsigned)d / (unsigned)npb;
        unsigned ld = (unsigned)d - b * (unsigned)npb;
        int off = atomicAdd(&lcur[b], 1);
        ebuf[base[b] + off] = (ld << 17) | (unsigned)src[e];  // contiguous runs
    }
}

// Per-bucket node histogram -> dinv only (csr no longer needed).
__global__ __launch_bounds__(1024) void k_hist(const unsigned* __restrict__ ebuf,
        const int* __restrict__ bstart, float* __restrict__ dinv, int N, int npb) {
    __shared__ int h[MAXNPB];
    int b = blockIdx.x, tid = threadIdx.x;
    int vlo = b * npb;
    int vcnt = min(npb, N - vlo);
    if (vcnt <= 0) return;                    // uniform across block
    for (int i = tid; i < MAXNPB; i += 1024) h[i] = 0;
    __syncthreads();
    int e0 = bstart[b], e1 = bstart[b + 1];
    for (int e = e0 + tid; e < e1; e += 1024)
        atomicAdd(&h[ebuf[e] >> 17], 1);
    __syncthreads();
    if (tid < vcnt) dinv[vlo + tid] = rsqrtf((float)(h[tid] + 1));
}

// hsb[v] = bf16x2-packed row of dinv[v] * (X[v] @ W1). X row in 2 VGPRs,
// inner loop = readlane + 1 LDS read + FMA. 8 nodes per wave.
#define GNPW 8
__global__ void k_gemm1(const float* __restrict__ X, const float* __restrict__ W,
                        const float* __restrict__ dinv, unsigned* __restrict__ hsb, int n) {
    __shared__ float Ws[128 * 64];
    for (int i = threadIdx.x; i < 128 * 64; i += 256) Ws[i] = W[i];
    __syncthreads();
    int lane = threadIdx.x & 63;
    int wv = threadIdx.x >> 6;
    int v0 = (blockIdx.x * 4 + wv) * GNPW;
    for (int nn = 0; nn < GNPW; ++nn) {
        int v = v0 + nn;
        if (v >= n) return;                   // wave-uniform
        const float* xr = X + (size_t)v * 128;
        float r0 = xr[lane], r1 = xr[64 + lane];
        float a0 = 0.f, a1 = 0.f, a2 = 0.f, a3 = 0.f;
#pragma unroll
        for (int k = 0; k < 64; k += 4) {
            a0 = fmaf(rdlane(r0, k + 0), Ws[(k + 0) * 64 + lane], a0);
            a1 = fmaf(rdlane(r0, k + 1), Ws[(k + 1) * 64 + lane], a1);
            a2 = fmaf(rdlane(r0, k + 2), Ws[(k + 2) * 64 + lane], a2);
            a3 = fmaf(rdlane(r0, k + 3), Ws[(k + 3) * 64 + lane], a3);
        }
#pragma unroll
        for (int k = 0; k < 64; k += 4) {
            a0 = fmaf(rdlane(r1, k + 0), Ws[(64 + k + 0) * 64 + lane], a0);
            a1 = fmaf(rdlane(r1, k + 1), Ws[(64 + k + 1) * 64 + lane], a1);
            a2 = fmaf(rdlane(r1, k + 2), Ws[(64 + k + 2) * 64 + lane], a2);
            a3 = fmaf(rdlane(r1, k + 3), Ws[(64 + k + 3) * 64 + lane], a3);
        }
        float val = ((a0 + a1) + (a2 + a3)) * dinv[v];
        float other = __shfl_xor(val, 1, 64);
        if ((lane & 1) == 0)
            hsb[(size_t)v * 32 + (lane >> 1)] = bf16_bits(val) | (bf16_bits(other) << 16);
    }
}

// Edge-streaming phase shared by both convs: 8-lane team per edge, unpack the
// 128B hs[src] row, ds_add_f32 into acc[ld*65 + f] (stride 65 spreads banks).
#define CONV_EDGE_PHASE                                                        \
    int b = blockIdx.x, tid = threadIdx.x;                                     \
    int vlo = b * npb;                                                         \
    int vcnt = min(npb, N - vlo);                                              \
    if (vcnt <= 0) return;                                                     \
    for (int i = tid; i < vcnt * 65; i += 1024) acc[i] = 0.f;                  \
    __syncthreads();                                                           \
    int e0 = bstart[b], e1 = bstart[b + 1];                                    \
    {                                                                          \
        int team = tid >> 3, o = tid & 7;                                      \
        const uint4* hs4p = (const uint4*)hsb;                                 \
        for (int e = e0 + team; e < e1; e += 128) {                            \
            unsigned ed = ebuf[e];                                             \
            int ld = ed >> 17;                                                 \
            int srcv = ed & 0x1FFFFu;                                          \
            uint4 wn = hs4p[(size_t)srcv * 8 + o];                             \
            float* a = &acc[ld * 65 + o * 8];                                  \
            atomicAdd(a + 0, bflo(wn.x)); atomicAdd(a + 1, bfhi(wn.x));        \
            atomicAdd(a + 2, bflo(wn.y)); atomicAdd(a + 3, bfhi(wn.y));        \
            atomicAdd(a + 4, bflo(wn.z)); atomicAdd(a + 5, bfhi(wn.z));        \
            atomicAdd(a + 6, bflo(wn.w)); atomicAdd(a + 7, bfhi(wn.w));        \
        }                                                                      \
    }                                                                          \
    __syncthreads();                                                           \
    int lane = tid & 63, wv = tid >> 6;

// conv1 + gemm2 fused. Epilogue: wave per node; h1[j] lives in lane j ->
// gemm2 via readlane against L1-resident W2.
__global__ __launch_bounds__(1024) void k_conv_mid(const unsigned* __restrict__ hsb,
        const unsigned* __restrict__ ebuf, const int* __restrict__ bstart,
        const float* __restrict__ dinv, const float* __restrict__ bias,
        const float* __restrict__ W2, unsigned* __restrict__ hsbB, int N, int npb) {
    __shared__ float acc[MAXNPB * 65];
    CONV_EDGE_PHASE
    for (int ld = wv; ld < vcnt; ld += 16) {
        int v = vlo + ld;
        float sum = acc[ld * 65 + lane];
        unsigned sd = hsb[(size_t)v * 32 + (lane >> 1)];
        float selfv = (lane & 1) ? bfhi(sd) : bflo(sd);
        float dv = dinv[v];
        float val = fmaxf(fmaf(dv, sum + selfv, bias[lane]), 0.f);
        float a2 = 0.f;
#pragma unroll
        for (int k = 0; k < 64; ++k)
            a2 = fmaf(rdlane(val, k), W2[k * 64 + lane], a2);
        float val2 = a2 * dv;
        float other = __shfl_xor(val2, 1, 64);
        if ((lane & 1) == 0)
            hsbB[(size_t)v * 32 + (lane >> 1)] = bf16_bits(val2) | (bf16_bits(other) << 16);
    }
}

// conv2 + head fused: z[v] = relu(...) @ Wl (2 floats per node).
__global__ __launch_bounds__(1024) void k_conv_out(const unsigned* __restrict__ hsb,
        const unsigned* __restrict__ ebuf, const int* __restrict__ bstart,
        const float* __restrict__ dinv, const float* __restrict__ bias,
        const float* __restrict__ Wl, float2* __restrict__ z, int N, int npb) {
    __shared__ float acc[MAXNPB * 65];
    CONV_EDGE_PHASE
    for (int ld = wv; ld < vcnt; ld += 16) {
        int v = vlo + ld;
        float sum = acc[ld * 65 + lane];
        unsigned sd = hsb[(size_t)v * 32 + (lane >> 1)];
        float selfv = (lane & 1) ? bfhi(sd) : bflo(sd);
        float dv = dinv[v];
        float val = fmaxf(fmaf(dv, sum + selfv, bias[lane]), 0.f);
        float2 wl = ((const float2*)Wl)[lane];
        float c0 = val * wl.x, c1 = val * wl.y;
        c0 += __shfl_xor(c0, 1, 64);  c1 += __shfl_xor(c1, 1, 64);
        c0 += __shfl_xor(c0, 2, 64);  c1 += __shfl_xor(c1, 2, 64);
        c0 += __shfl_xor(c0, 4, 64);  c1 += __shfl_xor(c1, 4, 64);
        c0 += __shfl_xor(c0, 8, 64);  c1 += __shfl_xor(c1, 8, 64);
        c0 += __shfl_xor(c0, 16, 64); c1 += __shfl_xor(c1, 16, 64);
        c0 += __shfl_xor(c0, 32, 64); c1 += __shfl_xor(c1, 32, 64);
        if (lane == 0) z[v] = make_float2(c0, c1);
    }
}

static __device__ __forceinline__ int lower_bound(const int* __restrict__ a, int n, int key) {
    int lo = 0, hi = n;
    while (lo < hi) {
        int mid = (lo + hi) >> 1;
        if (a[mid] < key) lo = mid + 1; else hi = mid;
    }
    return lo;
}

// One wave per graph: out[g] = mean(z[lo:hi]) + bl  (batch sorted).
__global__ void k_pool_z(const float2* __restrict__ z, const int* __restrict__ batch,
                         const float* __restrict__ bl, float* __restrict__ out, int N, int B) {
    int g = (blockIdx.x * 256 + threadIdx.x) >> 6;
    int lane = threadIdx.x & 63;
    if (g >= B) return;
    int lo = lower_bound(batch, N, g);
    int hi = lower_bound(batch, N, g + 1);
    float c0 = 0.f, c1 = 0.f;
    for (int v = lo + lane; v < hi; v += 64) {
        float2 t = z[v];
        c0 += t.x; c1 += t.y;
    }
    #pragma unroll
    for (int off = 32; off; off >>= 1) {
        c0 += __shfl_xor(c0, off, 64);
        c1 += __shfl_xor(c1, off, 64);
    }
    if (lane == 0) {
        float inv = 1.0f / fmaxf((float)(hi - lo), 1.0f);
        out[g * 2 + 0] = c0 * inv + bl[0];
        out[g * 2 + 1] = c1 * inv + bl[1];
    }
}

extern "C" void kernel_launch(void* const* d_in, const int* in_sizes, int n_in,
                              void* d_out, int out_size, void* d_ws, size_t ws_size,
                              hipStream_t stream) {
    const float* x  = (const float*)d_in[0];   // [N,128] f32
    const int* edge = (const int*)d_in[1];     // [2,E] i32
    const int* batch= (const int*)d_in[2];     // [N] i32 (sorted)
    const float* W1 = (const float*)d_in[3];   // [128,64]
    const float* b1 = (const float*)d_in[4];   // [64]
    const float* W2 = (const float*)d_in[5];   // [64,64]
    const float* b2 = (const float*)d_in[6];   // [64]
    const float* Wl = (const float*)d_in[7];   // [64,2]
    const float* bl = (const float*)d_in[8];   // [2]
    float* out = (float*)d_out;

    const int N = in_sizes[2];
    const int E = in_sizes[1] / 2;
    const int B = out_size / 2;
    const int* srcp = edge;
    const int* dstp = edge + E;
    const int npb = (N + NB - 1) / NB;         // nodes per bucket (196 @ N=100K, <=MAXNPB)

    // workspace carve-up (256B aligned); ~40 MB
    char* w = (char*)d_ws;
    auto carve = [&](size_t bytes) { void* p = (void*)w; w += (bytes + 255) & ~(size_t)255; return p; };
    float*    dinv    = (float*)carve((size_t)N * 4);
    int*      bcnt    = (int*)carve((NB + 8) * 4);
    int*      bstart  = (int*)carve((NB + 8) * 4);
    int*      blkhist = (int*)carve((size_t)SGRID * NB * 4);
    unsigned* ebuf    = (unsigned*)carve((size_t)E * 4);
    unsigned* hsbA    = (unsigned*)carve((size_t)N * 32 * 4);  // bf16x2 hs layer1
    unsigned* hsbB    = (unsigned*)carve((size_t)N * 32 * 4);  // bf16x2 hs layer2
    float2*   zbuf    = (float2*)carve((size_t)N * 8);         // per-node head output

    const int chunk = (E + SGRID - 1) / SGRID;  // edges per block

    k_bcount<<<SGRID, 1024, 0, stream>>>(dstp, blkhist, E, npb, chunk);
    k_bscan2<<<NB, SGRID, 0, stream>>>(blkhist, bcnt);
    k_bscan<<<1, 64, 0, stream>>>(bcnt, bstart);
    k_bscatter<<<SGRID, 1024, 0, stream>>>(srcp, dstp, bstart, blkhist, ebuf, E, npb, chunk);
    k_hist<<<NB, 1024, 0, stream>>>(ebuf, bstart, dinv, N, npb);

    k_gemm1<<<(N + 4 * GNPW - 1) / (4 * GNPW), 256, 0, stream>>>(x, W1, dinv, hsbA, N);
    k_conv_mid<<<NB, 1024, 0, stream>>>(hsbA, ebuf, bstart, dinv, b1, W2, hsbB, N, npb);
    k_conv_out<<<NB, 1024, 0, stream>>>(hsbB, ebuf, bstart, dinv, b2, Wl, zbuf, N, npb);

    k_pool_z<<<(B * 64 + 255) / 256, 256, 0, stream>>>(zbuf, batch, bl, out, N, B);
}

// Round 9
// 378.384 us; speedup vs baseline: 6.2047x; 6.2047x over previous
//
#include <hip/hip_runtime.h>
#include <hip/hip_bf16.h>

// GCN: h1 = relu(Dinv (A+I) Dinv (x W1) + b1); h2 = relu(same with W2);
// out = mean-pool-by-graph(h2) @ Wl + bl.
// Identity: hs[u] = (xW)[u]*dinv[u]; conv[v] = dinv[v]*(hs[v] + sum_in hs[u]) + b.
// R9: revert R8 (block-per-bucket LDS-atomic conv was 1-load-in-flight latency
// disaster: VALU 3.3%). Back to R7 wave-per-node gather, plus:
//  - gemm2 stripped from conv (readlane-gemm2 was 128 VALU/node) -> MFMA kernel
//  - gemm1 -> MFMA (16x16x32 bf16; W pre-swizzled into frag layout)
//  - gather fast path: 8 shfls + 8 uint4 loads issued back-to-back (8 in flight)

#define HDIM 64
#define NB 256      // dst-range buckets (N <= 131072: src fits 17 bits, local dst 9)
#define SGRID 256   // blocks for bcount/bscatter

typedef __attribute__((ext_vector_type(8))) short short8;   // 8 bf16 (4 VGPRs)
typedef __attribute__((ext_vector_type(4))) float f32x4;
union FragU { uint4 u; short8 s; };

static __device__ __forceinline__ unsigned bf16_bits(float f) {  // RNE
    unsigned u = __float_as_uint(f);
    return (u + 0x7fff + ((u >> 16) & 1)) >> 16;
}
static __device__ __forceinline__ float bflo(unsigned w) { return __uint_as_float(w << 16); }
static __device__ __forceinline__ float bfhi(unsigned w) { return __uint_as_float(w & 0xffff0000u); }

// ---------------- CSR build (counting sort by dst bucket) ----------------

__global__ __launch_bounds__(1024) void k_bcount(const int* __restrict__ dst,
        int* __restrict__ blkhist, int E, int npb, int chunk) {
    __shared__ int lh[NB];
    int tid = threadIdx.x;
    if (tid < NB) lh[tid] = 0;
    __syncthreads();
    int e0 = blockIdx.x * chunk, e1 = min(E, e0 + chunk);
    for (int e = e0 + tid; e < e1; e += 1024)
        atomicAdd(&lh[(unsigned)dst[e] / (unsigned)npb], 1);
    __syncthreads();
    if (tid < NB) blkhist[blockIdx.x * NB + tid] = lh[tid];
}

__global__ void k_bscan2(int* __restrict__ blkhist, int* __restrict__ bcnt) {
    __shared__ int s[SGRID];
    int b = blockIdx.x, t = threadIdx.x;
    int orig = blkhist[t * NB + b];
    s[t] = orig;
    __syncthreads();
    for (int off = 1; off < SGRID; off <<= 1) {
        int v = 0;
        if (t >= off) v = s[t - off];
        __syncthreads();
        s[t] += v;
        __syncthreads();
    }
    blkhist[t * NB + b] = s[t] - orig;        // exclusive prefix
    if (t == SGRID - 1) bcnt[b] = s[t];
}

__global__ void k_bscan(const int* __restrict__ bcnt, int* __restrict__ bstart) {
    if (threadIdx.x == 0) {
        int s = 0;
        for (int i = 0; i < NB; ++i) { bstart[i] = s; s += bcnt[i]; }
        bstart[NB] = s;
    }
}

__global__ __launch_bounds__(1024) void k_bscatter(const int* __restrict__ src,
        const int* __restrict__ dst, const int* __restrict__ bstart,
        const int* __restrict__ blkhist, unsigned* __restrict__ ebuf,
        int E, int npb, int chunk) {
    __shared__ int base[NB], lcur[NB];
    int tid = threadIdx.x;
    if (tid < NB) {
        base[tid] = bstart[tid] + blkhist[blockIdx.x * NB + tid];
        lcur[tid] = 0;
    }
    __syncthreads();
    int e0 = blockIdx.x * chunk, e1 = min(E, e0 + chunk);
    for (int e = e0 + tid; e < e1; e += 1024) {
        int d = dst[e];
        unsigned b = (unsigned)d / (unsigned)npb;
        unsigned ld = (unsigned)d - b * (unsigned)npb;
        int off = atomicAdd(&lcur[b], 1);
        ebuf[base[b] + off] = (ld << 17) | (unsigned)src[e];  // contiguous runs
    }
}

__global__ __launch_bounds__(1024) void k_bfill(const unsigned* __restrict__ ebuf,
        const int* __restrict__ bucket_start, int* __restrict__ row_start,
        int* __restrict__ cnt, float* __restrict__ dinv, int* __restrict__ csr,
        int N, int npb) {
    __shared__ int h[512], p[512], c[512];
    int b = blockIdx.x, tid = threadIdx.x;
    int vlo = b * npb;
    int vcnt = min(npb, N - vlo);
    if (vcnt <= 0) return;                    // uniform across block
    for (int i = tid; i < 512; i += 1024) h[i] = 0;
    __syncthreads();
    int e0 = bucket_start[b], e1 = bucket_start[b + 1];
    for (int e = e0 + tid; e < e1; e += 1024)
        atomicAdd(&h[ebuf[e] >> 17], 1);
    __syncthreads();
    if (tid < 512) p[tid] = h[tid];
    __syncthreads();
    for (int off = 1; off < 512; off <<= 1) { // Hillis-Steele inclusive scan
        int v = 0;
        if (tid < 512 && tid >= off) v = p[tid - off];
        __syncthreads();
        if (tid < 512) p[tid] += v;
        __syncthreads();
    }
    if (tid < vcnt) {
        int excl = p[tid] - h[tid];
        int v = vlo + tid;
        row_start[v] = e0 + excl;
        cnt[v] = h[tid];
        dinv[v] = rsqrtf((float)(h[tid] + 1));
        c[tid] = excl;
    }
    __syncthreads();
    for (int e = e0 + tid; e < e1; e += 1024) {
        unsigned ed = ebuf[e];
        int off = atomicAdd(&c[ed >> 17], 1);
        csr[e0 + off] = (int)(ed & 0x1FFFFu);
    }
}

// ---------------- weight swizzle for MFMA frag layout ----------------
// B-frag (16x16x32 bf16): lane holds B[k=(lane>>4)*8+j][n=lane&15], j=0..7.
// Wswz[((kt*4+nt)*64+lane)] = uint4 of the 8 bf16 (j pairs in uint lo/hi).
__global__ void k_prep(const float* __restrict__ W1, const float* __restrict__ W2,
                       uint4* __restrict__ W1s, uint4* __restrict__ W2s) {
    int t = threadIdx.x;
    int lane = t & 63, ci = t >> 6;
    {   // W1: K=128 -> 4 ktiles x 4 ntiles
        int kt = ci >> 2, nt = ci & 3;
        int kbase = kt * 32 + (lane >> 4) * 8;
        int n = nt * 16 + (lane & 15);
        uint4 o;
        unsigned* op = (unsigned*)&o;
        for (int jj = 0; jj < 4; ++jj) {
            unsigned lo = bf16_bits(W1[(kbase + 2 * jj) * 64 + n]);
            unsigned hi = bf16_bits(W1[(kbase + 2 * jj + 1) * 64 + n]);
            op[jj] = lo | (hi << 16);
        }
        W1s[ci * 64 + lane] = o;
    }
    if (ci < 8) {  // W2: K=64 -> 2 ktiles x 4 ntiles
        int kt = ci >> 2, nt = ci & 3;
        int kbase = kt * 32 + (lane >> 4) * 8;
        int n = nt * 16 + (lane & 15);
        uint4 o;
        unsigned* op = (unsigned*)&o;
        for (int jj = 0; jj < 4; ++jj) {
            unsigned lo = bf16_bits(W2[(kbase + 2 * jj) * 64 + n]);
            unsigned hi = bf16_bits(W2[(kbase + 2 * jj + 1) * 64 + n]);
            op[jj] = lo | (hi << 16);
        }
        W2s[ci * 64 + lane] = o;
    }
}

// ---------------- MFMA GEMMs ----------------
// Shared epilogue: D col=lane&15 (feature in ntile), row=(lane>>4)*4+r (node in 16).
#define MFMA_EPILOGUE(OUT)                                                     \
    {                                                                          \
        int col = lane & 15;                                                   \
        float dv[4];                                                           \
        for (int r = 0; r < 4; ++r) {                                          \
            int vr = v0 + quad * 4 + r;                                        \
            dv[r] = dinv[vr < n ? vr : (n - 1)];                               \
        }                                                                      \
        for (int nt = 0; nt < 4; ++nt)                                         \
            for (int r = 0; r < 4; ++r) {                                      \
                int vr = v0 + quad * 4 + r;                                    \
                float val = acc[nt][r] * dv[r];                                \
                float oth = __shfl_xor(val, 1, 64);                            \
                if (!(lane & 1) && vr < n)                                     \
                    OUT[(size_t)vr * 32 + nt * 8 + (col >> 1)] =               \
                        bf16_bits(val) | (bf16_bits(oth) << 16);               \
            }                                                                  \
    }

// hs1 = dinv * (X @ W1), X fp32 [N,128], out bf16x2-packed [N,32 uints]
__global__ __launch_bounds__(256) void k_mgemm1(const float* __restrict__ X,
        const uint4* __restrict__ W1s, const float* __restrict__ dinv,
        unsigned* __restrict__ hsb, int n) {
    int lane = threadIdx.x & 63, wv = threadIdx.x >> 6;
    int v0 = (blockIdx.x * 4 + wv) * 16;
    if (v0 >= n) return;                      // wave-uniform
    int quad = lane >> 4;
    int vm = v0 + (lane & 15); if (vm >= n) vm = n - 1;
    const float* xr = X + (size_t)vm * 128 + quad * 8;
    f32x4 acc[4] = {f32x4{0,0,0,0}, f32x4{0,0,0,0}, f32x4{0,0,0,0}, f32x4{0,0,0,0}};
#pragma unroll
    for (int kt = 0; kt < 4; ++kt) {
        float4 xa = *(const float4*)(xr + kt * 32);
        float4 xb = *(const float4*)(xr + kt * 32 + 4);
        FragU a;
        a.u.x = bf16_bits(xa.x) | (bf16_bits(xa.y) << 16);
        a.u.y = bf16_bits(xa.z) | (bf16_bits(xa.w) << 16);
        a.u.z = bf16_bits(xb.x) | (bf16_bits(xb.y) << 16);
        a.u.w = bf16_bits(xb.z) | (bf16_bits(xb.w) << 16);
#pragma unroll
        for (int nt = 0; nt < 4; ++nt) {
            FragU b; b.u = W1s[(kt * 4 + nt) * 64 + lane];
            acc[nt] = __builtin_amdgcn_mfma_f32_16x16x32_bf16(a.s, b.s, acc[nt], 0, 0, 0);
        }
    }
    MFMA_EPILOGUE(hsb)
}

// hs2 = dinv * (h1 @ W2), h1 bf16-packed [N,32 uints], out same format
__global__ __launch_bounds__(256) void k_mgemm2(const unsigned* __restrict__ h1b,
        const uint4* __restrict__ W2s, const float* __restrict__ dinv,
        unsigned* __restrict__ hsbB, int n) {
    int lane = threadIdx.x & 63, wv = threadIdx.x >> 6;
    int v0 = (blockIdx.x * 4 + wv) * 16;
    if (v0 >= n) return;
    int quad = lane >> 4;
    int vm = v0 + (lane & 15); if (vm >= n) vm = n - 1;
    const uint4* h4 = (const uint4*)h1b;
    f32x4 acc[4] = {f32x4{0,0,0,0}, f32x4{0,0,0,0}, f32x4{0,0,0,0}, f32x4{0,0,0,0}};
#pragma unroll
    for (int kt = 0; kt < 2; ++kt) {
        FragU a; a.u = h4[(size_t)vm * 8 + kt * 4 + quad];
#pragma unroll
        for (int nt = 0; nt < 4; ++nt) {
            FragU b; b.u = W2s[(kt * 4 + nt) * 64 + lane];
            acc[nt] = __builtin_amdgcn_mfma_f32_16x16x32_bf16(a.s, b.s, acc[nt], 0, 0, 0);
        }
    }
    MFMA_EPILOGUE(hsbB)
}

// ---------------- conv gather (wave per node) ----------------
// Eighth-wave: lane = oct*8+o; o picks uint4 (features 8o..8o+7); octs cover
// 8 neighbor rows per step. Fast path (full 64-edge block): 8 shfls + 8 loads
// issued before any accumulate -> 8 loads in flight.
#define GATHER_BODY                                                            \
    const uint4* hs4p = (const uint4*)hsb;                                     \
    int o = lane & 7, oct = lane >> 3;                                         \
    float a0=0.f,a1=0.f,a2=0.f,a3=0.f,a4=0.f,a5=0.f,a6=0.f,a7=0.f;             \
    if (oct == 0) {                                                            \
        uint4 s = hs4p[(size_t)v * 8 + o];                                     \
        a0=bflo(s.x);a1=bfhi(s.x);a2=bflo(s.y);a3=bfhi(s.y);                   \
        a4=bflo(s.z);a5=bfhi(s.z);a6=bflo(s.w);a7=bfhi(s.w);                   \
    }                                                                          \
    int rs = row_start[v], c = cnt[v];                                         \
    int base = 0;                                                              \
    for (; base + 64 <= c; base += 64) {                                       \
        int idx = csr[rs + base + lane];                                       \
        uint4 wbuf[8];                                                         \
        _Pragma("unroll")                                                      \
        for (int jj = 0; jj < 8; ++jj) {                                       \
            int u = __shfl(idx, jj * 8 + oct, 64);                             \
            wbuf[jj] = hs4p[(size_t)u * 8 + o];                                \
        }                                                                      \
        _Pragma("unroll")                                                      \
        for (int jj = 0; jj < 8; ++jj) {                                       \
            a0+=bflo(wbuf[jj].x);a1+=bfhi(wbuf[jj].x);                         \
            a2+=bflo(wbuf[jj].y);a3+=bfhi(wbuf[jj].y);                         \
            a4+=bflo(wbuf[jj].z);a5+=bfhi(wbuf[jj].z);                         \
            a6+=bflo(wbuf[jj].w);a7+=bfhi(wbuf[jj].w);                         \
        }                                                                      \
    }                                                                          \
    if (base < c) {                                                            \
        int m = c - base;                                                      \
        int idx = (lane < m) ? csr[rs + base + lane] : 0;                      \
        for (int j = 0; j < m; j += 8) {                                       \
            int u = __shfl(idx, j + oct, 64);                                  \
            if (j + oct < m) {                                                 \
                uint4 wn = hs4p[(size_t)u * 8 + o];                            \
                a0+=bflo(wn.x);a1+=bfhi(wn.x);a2+=bflo(wn.y);a3+=bfhi(wn.y);   \
                a4+=bflo(wn.z);a5+=bfhi(wn.z);a6+=bflo(wn.w);a7+=bfhi(wn.w);   \
            }                                                                  \
        }                                                                      \
    }                                                                          \
    a0+=__shfl_xor(a0,8,64);a0+=__shfl_xor(a0,16,64);a0+=__shfl_xor(a0,32,64); \
    a1+=__shfl_xor(a1,8,64);a1+=__shfl_xor(a1,16,64);a1+=__shfl_xor(a1,32,64); \
    a2+=__shfl_xor(a2,8,64);a2+=__shfl_xor(a2,16,64);a2+=__shfl_xor(a2,32,64); \
    a3+=__shfl_xor(a3,8,64);a3+=__shfl_xor(a3,16,64);a3+=__shfl_xor(a3,32,64); \
    a4+=__shfl_xor(a4,8,64);a4+=__shfl_xor(a4,16,64);a4+=__shfl_xor(a4,32,64); \
    a5+=__shfl_xor(a5,8,64);a5+=__shfl_xor(a5,16,64);a5+=__shfl_xor(a5,32,64); \
    a6+=__shfl_xor(a6,8,64);a6+=__shfl_xor(a6,16,64);a6+=__shfl_xor(a6,32,64); \
    a7+=__shfl_xor(a7,8,64);a7+=__shfl_xor(a7,16,64);a7+=__shfl_xor(a7,32,64); \
    float dv = dinv[v];                                                        \
    float4 bb0 = ((const float4*)bias)[2 * o];                                 \
    float4 bb1 = ((const float4*)bias)[2 * o + 1];                             \
    float r0 = fmaxf(fmaf(dv, a0, bb0.x), 0.f);                                \
    float r1 = fmaxf(fmaf(dv, a1, bb0.y), 0.f);                                \
    float r2 = fmaxf(fmaf(dv, a2, bb0.z), 0.f);                                \
    float r3 = fmaxf(fmaf(dv, a3, bb0.w), 0.f);                                \
    float r4 = fmaxf(fmaf(dv, a4, bb1.x), 0.f);                                \
    float r5 = fmaxf(fmaf(dv, a5, bb1.y), 0.f);                                \
    float r6 = fmaxf(fmaf(dv, a6, bb1.z), 0.f);                                \
    float r7 = fmaxf(fmaf(dv, a7, bb1.w), 0.f);

// conv1: gather hs1, h1 = relu(dinv*acc + b1), store h1 bf16-packed (uint4 from
// oct==0 lanes; the full row is replicated across octs after the reductions).
__global__ void k_conv1(const unsigned* __restrict__ hsb, const int* __restrict__ row_start,
                        const int* __restrict__ cnt, const int* __restrict__ csr,
                        const float* __restrict__ dinv, const float* __restrict__ bias,
                        unsigned* __restrict__ h1b, int n) {
    int v = (blockIdx.x * 256 + threadIdx.x) >> 6;
    int lane = threadIdx.x & 63;
    if (v >= n) return;
    GATHER_BODY
    if (oct == 0) {
        uint4 pk;
        pk.x = bf16_bits(r0) | (bf16_bits(r1) << 16);
        pk.y = bf16_bits(r2) | (bf16_bits(r3) << 16);
        pk.z = bf16_bits(r4) | (bf16_bits(r5) << 16);
        pk.w = bf16_bits(r6) | (bf16_bits(r7) << 16);
        ((uint4*)h1b)[(size_t)v * 8 + o] = pk;
    }
}

// conv2 + head: gather hs2, h2 = relu(dinv*acc + b2), z[v] = h2 @ Wl.
__global__ void k_conv_out(const unsigned* __restrict__ hsb, const int* __restrict__ row_start,
                           const int* __restrict__ cnt, const int* __restrict__ csr,
                           const float* __restrict__ dinv, const float* __restrict__ bias,
                           const float* __restrict__ Wl, float2* __restrict__ z, int n) {
    int v = (blockIdx.x * 256 + threadIdx.x) >> 6;
    int lane = threadIdx.x & 63;
    if (v >= n) return;
    GATHER_BODY
    const float4* Wl4 = (const float4*)Wl;    // [64][2] -> 2 rows per float4
    float4 wA = Wl4[4 * o + 0];
    float4 wB = Wl4[4 * o + 1];
    float4 wC = Wl4[4 * o + 2];
    float4 wD = Wl4[4 * o + 3];
    float c0 = r0*wA.x + r1*wA.z + r2*wB.x + r3*wB.z + r4*wC.x + r5*wC.z + r6*wD.x + r7*wD.z;
    float c1 = r0*wA.y + r1*wA.w + r2*wB.y + r3*wB.w + r4*wC.y + r5*wC.w + r6*wD.y + r7*wD.w;
    c0 += __shfl_xor(c0, 1, 64); c1 += __shfl_xor(c1, 1, 64);
    c0 += __shfl_xor(c0, 2, 64); c1 += __shfl_xor(c1, 2, 64);
    c0 += __shfl_xor(c0, 4, 64); c1 += __shfl_xor(c1, 4, 64);
    if (lane == 0) z[v] = make_float2(c0, c1);
}

static __device__ __forceinline__ int lower_bound(const int* __restrict__ a, int n, int key) {
    int lo = 0, hi = n;
    while (lo < hi) {
        int mid = (lo + hi) >> 1;
        if (a[mid] < key) lo = mid + 1; else hi = mid;
    }
    return lo;
}

// One wave per graph: out[g] = mean(z[lo:hi]) + bl  (batch sorted).
__global__ void k_pool_z(const float2* __restrict__ z, const int* __restrict__ batch,
                         const float* __restrict__ bl, float* __restrict__ out, int N, int B) {
    int g = (blockIdx.x * 256 + threadIdx.x) >> 6;
    int lane = threadIdx.x & 63;
    if (g >= B) return;
    int lo = lower_bound(batch, N, g);
    int hi = lower_bound(batch, N, g + 1);
    float c0 = 0.f, c1 = 0.f;
    for (int v = lo + lane; v < hi; v += 64) {
        float2 t = z[v];
        c0 += t.x; c1 += t.y;
    }
    #pragma unroll
    for (int off = 32; off; off >>= 1) {
        c0 += __shfl_xor(c0, off, 64);
        c1 += __shfl_xor(c1, off, 64);
    }
    if (lane == 0) {
        float inv = 1.0f / fmaxf((float)(hi - lo), 1.0f);
        out[g * 2 + 0] = c0 * inv + bl[0];
        out[g * 2 + 1] = c1 * inv + bl[1];
    }
}

extern "C" void kernel_launch(void* const* d_in, const int* in_sizes, int n_in,
                              void* d_out, int out_size, void* d_ws, size_t ws_size,
                              hipStream_t stream) {
    const float* x  = (const float*)d_in[0];   // [N,128] f32
    const int* edge = (const int*)d_in[1];     // [2,E] i32
    const int* batch= (const int*)d_in[2];     // [N] i32 (sorted)
    const float* W1 = (const float*)d_in[3];   // [128,64]
    const float* b1 = (const float*)d_in[4];   // [64]
    const float* W2 = (const float*)d_in[5];   // [64,64]
    const float* b2 = (const float*)d_in[6];   // [64]
    const float* Wl = (const float*)d_in[7];   // [64,2]
    const float* bl = (const float*)d_in[8];   // [2]
    float* out = (float*)d_out;

    const int N = in_sizes[2];
    const int E = in_sizes[1] / 2;
    const int B = out_size / 2;
    const int* srcp = edge;
    const int* dstp = edge + E;
    const int npb = (N + NB - 1) / NB;         // nodes per bucket (391 @ N=100K, <=512)

    // workspace carve-up (256B aligned); ~68 MB
    char* w = (char*)d_ws;
    auto carve = [&](size_t bytes) { void* p = (void*)w; w += (bytes + 255) & ~(size_t)255; return p; };
    int*      cnt     = (int*)carve((size_t)N * 4);
    int*      rsA     = (int*)carve((size_t)N * 4);
    float*    dinv    = (float*)carve((size_t)N * 4);
    int*      bcnt    = (int*)carve((NB + 8) * 4);
    int*      bstart  = (int*)carve((NB + 8) * 4);
    int*      blkhist = (int*)carve((size_t)SGRID * NB * 4);
    uint4*    W1s     = (uint4*)carve(16 * 64 * 16);
    uint4*    W2s     = (uint4*)carve(8 * 64 * 16);
    int*      csr     = (int*)carve((size_t)E * 4);
    unsigned* ebuf    = (unsigned*)carve((size_t)E * 4);
    unsigned* hsbA    = (unsigned*)carve((size_t)N * 32 * 4);  // bf16x2 hs layer1
    unsigned* h1b     = (unsigned*)carve((size_t)N * 32 * 4);  // bf16x2 relu'd h1
    unsigned* hsbB    = (unsigned*)carve((size_t)N * 32 * 4);  // bf16x2 hs layer2
    float2*   zbuf    = (float2*)carve((size_t)N * 8);         // per-node head output

    const int chunk = (E + SGRID - 1) / SGRID;  // edges per block
    int wbl = (N + 3) / 4;                      // 4 waves (nodes) per 256-thread block
    int gbl = (N + 63) / 64;                    // 64 nodes per MFMA-gemm block

    k_prep<<<1, 1024, 0, stream>>>(W1, W2, W1s, W2s);
    k_bcount<<<SGRID, 1024, 0, stream>>>(dstp, blkhist, E, npb, chunk);
    k_bscan2<<<NB, SGRID, 0, stream>>>(blkhist, bcnt);
    k_bscan<<<1, 64, 0, stream>>>(bcnt, bstart);
    k_bscatter<<<SGRID, 1024, 0, stream>>>(srcp, dstp, bstart, blkhist, ebuf, E, npb, chunk);
    k_bfill<<<NB, 1024, 0, stream>>>(ebuf, bstart, rsA, cnt, dinv, csr, N, npb);

    k_mgemm1<<<gbl, 256, 0, stream>>>(x, W1s, dinv, hsbA, N);
    k_conv1<<<wbl, 256, 0, stream>>>(hsbA, rsA, cnt, csr, dinv, b1, h1b, N);
    k_mgemm2<<<gbl, 256, 0, stream>>>(h1b, W2s, dinv, hsbB, N);
    k_conv_out<<<wbl, 256, 0, stream>>>(hsbB, rsA, cnt, csr, dinv, b2, Wl, zbuf, N);

    k_pool_z<<<(B * 64 + 255) / 256, 256, 0, stream>>>(zbuf, batch, bl, out, N, B);
}

// Round 10
// 324.939 us; speedup vs baseline: 7.2253x; 1.1645x over previous
//
#include <hip/hip_runtime.h>
#include <hip/hip_bf16.h>

// GCN: h1 = relu(Dinv (A+I) Dinv (x W1) + b1); h2 = relu(same with W2);
// out = mean-pool-by-graph(h2) @ Wl + bl.
// Identity: hs[u] = (xW)[u]*dinv[u]; conv[v] = dinv[v]*(hs[v] + sum_in hs[u]) + b.
// R10: (a) CSR rows padded to %8 with dummy src=N whose hs row is zero ->
// gather loop is branch-free, loads issued in groups (R9's "fast path" never
// ran: degree~Poisson(32) < 64, tail path had ~1 load in flight);
// (b) k_bscan was a 1-thread serial 256-iter loop (~30us latency) -> parallel
// scan; (c) ebuf aliases hsbA (ebuf dead before mgemm1 writes).

#define HDIM 64
#define NB 256      // dst-range buckets (N <= 131072: src fits 17 bits, local dst 9)
#define SGRID 256   // blocks for bcount/bscatter

typedef __attribute__((ext_vector_type(8))) short short8;   // 8 bf16 (4 VGPRs)
typedef __attribute__((ext_vector_type(4))) float f32x4;
union FragU { uint4 u; short8 s; };

static __device__ __forceinline__ unsigned bf16_bits(float f) {  // RNE
    unsigned u = __float_as_uint(f);
    return (u + 0x7fff + ((u >> 16) & 1)) >> 16;
}
static __device__ __forceinline__ float bflo(unsigned w) { return __uint_as_float(w << 16); }
static __device__ __forceinline__ float bfhi(unsigned w) { return __uint_as_float(w & 0xffff0000u); }

// ---------------- CSR build (counting sort by dst bucket) ----------------

__global__ __launch_bounds__(1024) void k_bcount(const int* __restrict__ dst,
        int* __restrict__ blkhist, int E, int npb, int chunk) {
    __shared__ int lh[NB];
    int tid = threadIdx.x;
    if (tid < NB) lh[tid] = 0;
    __syncthreads();
    int e0 = blockIdx.x * chunk, e1 = min(E, e0 + chunk);
    for (int e = e0 + tid; e < e1; e += 1024)
        atomicAdd(&lh[(unsigned)dst[e] / (unsigned)npb], 1);
    __syncthreads();
    if (tid < NB) blkhist[blockIdx.x * NB + tid] = lh[tid];
}

__global__ void k_bscan2(int* __restrict__ blkhist, int* __restrict__ bcnt) {
    __shared__ int s[SGRID];
    int b = blockIdx.x, t = threadIdx.x;
    int orig = blkhist[t * NB + b];
    s[t] = orig;
    __syncthreads();
    for (int off = 1; off < SGRID; off <<= 1) {
        int v = 0;
        if (t >= off) v = s[t - off];
        __syncthreads();
        s[t] += v;
        __syncthreads();
    }
    blkhist[t * NB + b] = s[t] - orig;        // exclusive prefix
    if (t == SGRID - 1) bcnt[b] = s[t];
}

// Parallel exclusive scan over NB buckets (R9's serial 1-thread loop was ~30us).
__global__ void k_bscan(const int* __restrict__ bcnt, int* __restrict__ bstart) {
    __shared__ int s[NB];
    int t = threadIdx.x;
    int orig = bcnt[t];
    s[t] = orig;
    __syncthreads();
    for (int off = 1; off < NB; off <<= 1) {
        int v = 0;
        if (t >= off) v = s[t - off];
        __syncthreads();
        s[t] += v;
        __syncthreads();
    }
    bstart[t] = s[t] - orig;
    if (t == NB - 1) bstart[NB] = s[t];
}

__global__ __launch_bounds__(1024) void k_bscatter(const int* __restrict__ src,
        const int* __restrict__ dst, const int* __restrict__ bstart,
        const int* __restrict__ blkhist, unsigned* __restrict__ ebuf,
        int E, int npb, int chunk) {
    __shared__ int base[NB], lcur[NB];
    int tid = threadIdx.x;
    if (tid < NB) {
        base[tid] = bstart[tid] + blkhist[blockIdx.x * NB + tid];
        lcur[tid] = 0;
    }
    __syncthreads();
    int e0 = blockIdx.x * chunk, e1 = min(E, e0 + chunk);
    for (int e = e0 + tid; e < e1; e += 1024) {
        int d = dst[e];
        unsigned b = (unsigned)d / (unsigned)npb;
        unsigned ld = (unsigned)d - b * (unsigned)npb;
        int off = atomicAdd(&lcur[b], 1);
        ebuf[base[b] + off] = (ld << 17) | (unsigned)src[e];  // contiguous runs
    }
}

// One WG per bucket: histogram -> padded scan -> row_start/cnt8/dinv + csr fill
// (+ zero-row padding to a multiple of 8 edges per node, dummy src = N).
__global__ __launch_bounds__(1024) void k_bfill(const unsigned* __restrict__ ebuf,
        const int* __restrict__ bstart, int* __restrict__ row_start,
        int* __restrict__ cnt8, float* __restrict__ dinv, int* __restrict__ csr,
        int N, int npb) {
    __shared__ int h[512], p[512], c[512];
    int b = blockIdx.x, tid = threadIdx.x;
    int vlo = b * npb;
    int vcnt = min(npb, N - vlo);
    if (vcnt <= 0) return;                    // uniform across block
    for (int i = tid; i < 512; i += 1024) h[i] = 0;
    __syncthreads();
    int e0 = bstart[b], e1 = bstart[b + 1];
    for (int e = e0 + tid; e < e1; e += 1024)
        atomicAdd(&h[ebuf[e] >> 17], 1);
    __syncthreads();
    int pc = 0;
    if (tid < 512) {
        pc = (tid < vcnt) ? ((h[tid] + 7) & ~7) : 0;   // padded count
        p[tid] = pc;
    }
    __syncthreads();
    for (int off = 1; off < 512; off <<= 1) { // Hillis-Steele inclusive scan
        int v = 0;
        if (tid < 512 && tid >= off) v = p[tid - off];
        __syncthreads();
        if (tid < 512) p[tid] += v;
        __syncthreads();
    }
    int bb = e0 + 7 * vlo;                    // padded bucket base (csr sized E+7N)
    if (tid < vcnt) {
        int excl = p[tid] - pc;
        int v = vlo + tid;
        row_start[v] = bb + excl;
        cnt8[v] = pc >> 3;
        dinv[v] = rsqrtf((float)(h[tid] + 1));
        c[tid] = excl;
    }
    __syncthreads();
    for (int e = e0 + tid; e < e1; e += 1024) {
        unsigned ed = ebuf[e];
        int off = atomicAdd(&c[ed >> 17], 1);
        csr[bb + off] = (int)(ed & 0x1FFFFu);
    }
    __syncthreads();
    if (tid < vcnt) {                         // zero-row padding entries
        int excl = p[tid] - pc;
        for (int q = excl + h[tid]; q < excl + pc; ++q) csr[bb + q] = N;
    }
}

// ---------------- weight swizzle for MFMA frag layout + zero rows ----------
// B-frag (16x16x32 bf16): lane holds B[k=(lane>>4)*8+j][n=lane&15], j=0..7.
__global__ void k_prep(const float* __restrict__ W1, const float* __restrict__ W2,
                       uint4* __restrict__ W1s, uint4* __restrict__ W2s,
                       unsigned* __restrict__ hsbA, unsigned* __restrict__ hsbB, int N) {
    int t = threadIdx.x;
    int lane = t & 63, ci = t >> 6;
    {   // W1: K=128 -> 4 ktiles x 4 ntiles
        int kt = ci >> 2, nt = ci & 3;
        int kbase = kt * 32 + (lane >> 4) * 8;
        int n = nt * 16 + (lane & 15);
        uint4 o;
        unsigned* op = (unsigned*)&o;
        for (int jj = 0; jj < 4; ++jj) {
            unsigned lo = bf16_bits(W1[(kbase + 2 * jj) * 64 + n]);
            unsigned hi = bf16_bits(W1[(kbase + 2 * jj + 1) * 64 + n]);
            op[jj] = lo | (hi << 16);
        }
        W1s[ci * 64 + lane] = o;
    }
    if (ci < 8) {  // W2: K=64 -> 2 ktiles x 4 ntiles
        int kt = ci >> 2, nt = ci & 3;
        int kbase = kt * 32 + (lane >> 4) * 8;
        int n = nt * 16 + (lane & 15);
        uint4 o;
        unsigned* op = (unsigned*)&o;
        for (int jj = 0; jj < 4; ++jj) {
            unsigned lo = bf16_bits(W2[(kbase + 2 * jj) * 64 + n]);
            unsigned hi = bf16_bits(W2[(kbase + 2 * jj + 1) * 64 + n]);
            op[jj] = lo | (hi << 16);
        }
        W2s[ci * 64 + lane] = o;
    }
    // zero row N of both gather tables (padding target). NOTE: hsbA aliases
    // ebuf, but row N starts at byte E*4 == end of ebuf's used range (E=32N).
    if (t < 32) hsbA[(size_t)N * 32 + t] = 0;
    else if (t < 64) hsbB[(size_t)N * 32 + (t - 32)] = 0;
}

// ---------------- MFMA GEMMs ----------------
// D col=lane&15 (feature in ntile), row=(lane>>4)*4+r (node in 16).
#define MFMA_EPILOGUE(OUT)                                                     \
    {                                                                          \
        int col = lane & 15;                                                   \
        float dv[4];                                                           \
        for (int r = 0; r < 4; ++r) {                                          \
            int vr = v0 + quad * 4 + r;                                        \
            dv[r] = dinv[vr < n ? vr : (n - 1)];                               \
        }                                                                      \
        for (int nt = 0; nt < 4; ++nt)                                         \
            for (int r = 0; r < 4; ++r) {                                      \
                int vr = v0 + quad * 4 + r;                                    \
                float val = acc[nt][r] * dv[r];                                \
                float oth = __shfl_xor(val, 1, 64);                            \
                if (!(lane & 1) && vr < n)                                     \
                    OUT[(size_t)vr * 32 + nt * 8 + (col >> 1)] =               \
                        bf16_bits(val) | (bf16_bits(oth) << 16);               \
            }                                                                  \
    }

// hs1 = dinv * (X @ W1), X fp32 [N,128], out bf16x2-packed [N,32 uints]
__global__ __launch_bounds__(256) void k_mgemm1(const float* __restrict__ X,
        const uint4* __restrict__ W1s, const float* __restrict__ dinv,
        unsigned* __restrict__ hsb, int n) {
    int lane = threadIdx.x & 63, wv = threadIdx.x >> 6;
    int v0 = (blockIdx.x * 4 + wv) * 16;
    if (v0 >= n) return;                      // wave-uniform
    int quad = lane >> 4;
    int vm = v0 + (lane & 15); if (vm >= n) vm = n - 1;
    const float* xr = X + (size_t)vm * 128 + quad * 8;
    f32x4 acc[4] = {f32x4{0,0,0,0}, f32x4{0,0,0,0}, f32x4{0,0,0,0}, f32x4{0,0,0,0}};
#pragma unroll
    for (int kt = 0; kt < 4; ++kt) {
        float4 xa = *(const float4*)(xr + kt * 32);
        float4 xb = *(const float4*)(xr + kt * 32 + 4);
        FragU a;
        a.u.x = bf16_bits(xa.x) | (bf16_bits(xa.y) << 16);
        a.u.y = bf16_bits(xa.z) | (bf16_bits(xa.w) << 16);
        a.u.z = bf16_bits(xb.x) | (bf16_bits(xb.y) << 16);
        a.u.w = bf16_bits(xb.z) | (bf16_bits(xb.w) << 16);
#pragma unroll
        for (int nt = 0; nt < 4; ++nt) {
            FragU b; b.u = W1s[(kt * 4 + nt) * 64 + lane];
            acc[nt] = __builtin_amdgcn_mfma_f32_16x16x32_bf16(a.s, b.s, acc[nt], 0, 0, 0);
        }
    }
    MFMA_EPILOGUE(hsb)
}

// hs2 = dinv * (h1 @ W2), h1 bf16-packed [N,32 uints], out same format
__global__ __launch_bounds__(256) void k_mgemm2(const unsigned* __restrict__ h1b,
        const uint4* __restrict__ W2s, const float* __restrict__ dinv,
        unsigned* __restrict__ hsbB, int n) {
    int lane = threadIdx.x & 63, wv = threadIdx.x >> 6;
    int v0 = (blockIdx.x * 4 + wv) * 16;
    if (v0 >= n) return;
    int quad = lane >> 4;
    int vm = v0 + (lane & 15); if (vm >= n) vm = n - 1;
    const uint4* h4 = (const uint4*)h1b;
    f32x4 acc[4] = {f32x4{0,0,0,0}, f32x4{0,0,0,0}, f32x4{0,0,0,0}, f32x4{0,0,0,0}};
#pragma unroll
    for (int kt = 0; kt < 2; ++kt) {
        FragU a; a.u = h4[(size_t)vm * 8 + kt * 4 + quad];
#pragma unroll
        for (int nt = 0; nt < 4; ++nt) {
            FragU b; b.u = W2s[(kt * 4 + nt) * 64 + lane];
            acc[nt] = __builtin_amdgcn_mfma_f32_16x16x32_bf16(a.s, b.s, acc[nt], 0, 0, 0);
        }
    }
    MFMA_EPILOGUE(hsbB)
}

// ---------------- conv gather (wave per node, padded branch-free) -----------
// lane = oct*8+o; o picks uint4 (features 8o..8o+7); octs cover 8 edges/chunk.
// Rows padded to whole chunks; per 8-chunk group all <=8 loads issue under
// wave-uniform scalar guards (no exec-mask divergence) -> high MLP.
#define GATHER_BODY                                                            \
    const uint4* hs4p = (const uint4*)hsb;                                     \
    int o = lane & 7, oct = lane >> 3;                                         \
    float a0=0.f,a1=0.f,a2=0.f,a3=0.f,a4=0.f,a5=0.f,a6=0.f,a7=0.f;             \
    if (oct == 0) {                                                            \
        uint4 s = hs4p[(size_t)v * 8 + o];                                     \
        a0=bflo(s.x);a1=bfhi(s.x);a2=bflo(s.y);a3=bfhi(s.y);                   \
        a4=bflo(s.z);a5=bfhi(s.z);a6=bflo(s.w);a7=bfhi(s.w);                   \
    }                                                                          \
    int rs = row_start[v], nb = cnt8[v];                                       \
    for (int base = 0; base < nb; base += 8) {                                 \
        int idx = csr[rs + base * 8 + lane];  /* overread ok: csr has slack */ \
        int m = nb - base; if (m > 8) m = 8;  /* wave-uniform */               \
        uint4 wb[8];                                                           \
        _Pragma("unroll")                                                      \
        for (int i = 0; i < 8; ++i)                                            \
            if (i < m) {                                                       \
                int u = __shfl(idx, i * 8 + oct, 64);                          \
                wb[i] = hs4p[(size_t)u * 8 + o];                               \
            }                                                                  \
        _Pragma("unroll")                                                      \
        for (int i = 0; i < 8; ++i)                                            \
            if (i < m) {                                                       \
                a0+=bflo(wb[i].x);a1+=bfhi(wb[i].x);                           \
                a2+=bflo(wb[i].y);a3+=bfhi(wb[i].y);                           \
                a4+=bflo(wb[i].z);a5+=bfhi(wb[i].z);                           \
                a6+=bflo(wb[i].w);a7+=bfhi(wb[i].w);                           \
            }                                                                  \
    }                                                                          \
    a0+=__shfl_xor(a0,8,64);a0+=__shfl_xor(a0,16,64);a0+=__shfl_xor(a0,32,64); \
    a1+=__shfl_xor(a1,8,64);a1+=__shfl_xor(a1,16,64);a1+=__shfl_xor(a1,32,64); \
    a2+=__shfl_xor(a2,8,64);a2+=__shfl_xor(a2,16,64);a2+=__shfl_xor(a2,32,64); \
    a3+=__shfl_xor(a3,8,64);a3+=__shfl_xor(a3,16,64);a3+=__shfl_xor(a3,32,64); \
    a4+=__shfl_xor(a4,8,64);a4+=__shfl_xor(a4,16,64);a4+=__shfl_xor(a4,32,64); \
    a5+=__shfl_xor(a5,8,64);a5+=__shfl_xor(a5,16,64);a5+=__shfl_xor(a5,32,64); \
    a6+=__shfl_xor(a6,8,64);a6+=__shfl_xor(a6,16,64);a6+=__shfl_xor(a6,32,64); \
    a7+=__shfl_xor(a7,8,64);a7+=__shfl_xor(a7,16,64);a7+=__shfl_xor(a7,32,64); \
    float dv = dinv[v];                                                        \
    float4 bb0 = ((const float4*)bias)[2 * o];                                 \
    float4 bb1 = ((const float4*)bias)[2 * o + 1];                             \
    float r0 = fmaxf(fmaf(dv, a0, bb0.x), 0.f);                                \
    float r1 = fmaxf(fmaf(dv, a1, bb0.y), 0.f);                                \
    float r2 = fmaxf(fmaf(dv, a2, bb0.z), 0.f);                                \
    float r3 = fmaxf(fmaf(dv, a3, bb0.w), 0.f);                                \
    float r4 = fmaxf(fmaf(dv, a4, bb1.x), 0.f);                                \
    float r5 = fmaxf(fmaf(dv, a5, bb1.y), 0.f);                                \
    float r6 = fmaxf(fmaf(dv, a6, bb1.z), 0.f);                                \
    float r7 = fmaxf(fmaf(dv, a7, bb1.w), 0.f);

// conv1: gather hs1, h1 = relu(dinv*acc + b1), store h1 bf16-packed.
__global__ void k_conv1(const unsigned* __restrict__ hsb, const int* __restrict__ row_start,
                        const int* __restrict__ cnt8, const int* __restrict__ csr,
                        const float* __restrict__ dinv, const float* __restrict__ bias,
                        unsigned* __restrict__ h1b, int n) {
    int v = (blockIdx.x * 256 + threadIdx.x) >> 6;
    int lane = threadIdx.x & 63;
    if (v >= n) return;
    GATHER_BODY
    if (oct == 0) {
        uint4 pk;
        pk.x = bf16_bits(r0) | (bf16_bits(r1) << 16);
        pk.y = bf16_bits(r2) | (bf16_bits(r3) << 16);
        pk.z = bf16_bits(r4) | (bf16_bits(r5) << 16);
        pk.w = bf16_bits(r6) | (bf16_bits(r7) << 16);
        ((uint4*)h1b)[(size_t)v * 8 + o] = pk;
    }
}

// conv2 + head: gather hs2, h2 = relu(dinv*acc + b2), z[v] = h2 @ Wl.
__global__ void k_conv_out(const unsigned* __restrict__ hsb, const int* __restrict__ row_start,
                           const int* __restrict__ cnt8, const int* __restrict__ csr,
                           const float* __restrict__ dinv, const float* __restrict__ bias,
                           const float* __restrict__ Wl, float2* __restrict__ z, int n) {
    int v = (blockIdx.x * 256 + threadIdx.x) >> 6;
    int lane = threadIdx.x & 63;
    if (v >= n) return;
    GATHER_BODY
    const float4* Wl4 = (const float4*)Wl;    // [64][2] -> 2 rows per float4
    float4 wA = Wl4[4 * o + 0];
    float4 wB = Wl4[4 * o + 1];
    float4 wC = Wl4[4 * o + 2];
    float4 wD = Wl4[4 * o + 3];
    float c0 = r0*wA.x + r1*wA.z + r2*wB.x + r3*wB.z + r4*wC.x + r5*wC.z + r6*wD.x + r7*wD.z;
    float c1 = r0*wA.y + r1*wA.w + r2*wB.y + r3*wB.w + r4*wC.y + r5*wC.w + r6*wD.y + r7*wD.w;
    c0 += __shfl_xor(c0, 1, 64); c1 += __shfl_xor(c1, 1, 64);
    c0 += __shfl_xor(c0, 2, 64); c1 += __shfl_xor(c1, 2, 64);
    c0 += __shfl_xor(c0, 4, 64); c1 += __shfl_xor(c1, 4, 64);
    if (lane == 0) z[v] = make_float2(c0, c1);
}

static __device__ __forceinline__ int lower_bound(const int* __restrict__ a, int n, int key) {
    int lo = 0, hi = n;
    while (lo < hi) {
        int mid = (lo + hi) >> 1;
        if (a[mid] < key) lo = mid + 1; else hi = mid;
    }
    return lo;
}

// One wave per graph: out[g] = mean(z[lo:hi]) + bl  (batch sorted).
__global__ void k_pool_z(const float2* __restrict__ z, const int* __restrict__ batch,
                         const float* __restrict__ bl, float* __restrict__ out, int N, int B) {
    int g = (blockIdx.x * 256 + threadIdx.x) >> 6;
    int lane = threadIdx.x & 63;
    if (g >= B) return;
    int lo = lower_bound(batch, N, g);
    int hi = lower_bound(batch, N, g + 1);
    float c0 = 0.f, c1 = 0.f;
    for (int v = lo + lane; v < hi; v += 64) {
        float2 t = z[v];
        c0 += t.x; c1 += t.y;
    }
    #pragma unroll
    for (int off = 32; off; off >>= 1) {
        c0 += __shfl_xor(c0, off, 64);
        c1 += __shfl_xor(c1, off, 64);
    }
    if (lane == 0) {
        float inv = 1.0f / fmaxf((float)(hi - lo), 1.0f);
        out[g * 2 + 0] = c0 * inv + bl[0];
        out[g * 2 + 1] = c1 * inv + bl[1];
    }
}

extern "C" void kernel_launch(void* const* d_in, const int* in_sizes, int n_in,
                              void* d_out, int out_size, void* d_ws, size_t ws_size,
                              hipStream_t stream) {
    const float* x  = (const float*)d_in[0];   // [N,128] f32
    const int* edge = (const int*)d_in[1];     // [2,E] i32
    const int* batch= (const int*)d_in[2];     // [N] i32 (sorted)
    const float* W1 = (const float*)d_in[3];   // [128,64]
    const float* b1 = (const float*)d_in[4];   // [64]
    const float* W2 = (const float*)d_in[5];   // [64,64]
    const float* b2 = (const float*)d_in[6];   // [64]
    const float* Wl = (const float*)d_in[7];   // [64,2]
    const float* bl = (const float*)d_in[8];   // [2]
    float* out = (float*)d_out;

    const int N = in_sizes[2];
    const int E = in_sizes[1] / 2;
    const int B = out_size / 2;
    const int* srcp = edge;
    const int* dstp = edge + E;
    const int npb = (N + NB - 1) / NB;         // nodes per bucket (391 @ N=100K, <=512)

    // workspace carve-up (256B aligned); ~58 MB
    char* w = (char*)d_ws;
    auto carve = [&](size_t bytes) { void* p = (void*)w; w += (bytes + 255) & ~(size_t)255; return p; };
    int*      cnt8    = (int*)carve((size_t)N * 4);
    int*      rsA     = (int*)carve((size_t)N * 4);
    float*    dinv    = (float*)carve((size_t)N * 4);
    int*      bcnt    = (int*)carve((NB + 8) * 4);
    int*      bstart  = (int*)carve((NB + 8) * 4);
    int*      blkhist = (int*)carve((size_t)SGRID * NB * 4);
    uint4*    W1s     = (uint4*)carve(16 * 64 * 16);
    uint4*    W2s     = (uint4*)carve(8 * 64 * 16);
    int*      csr     = (int*)carve(((size_t)E + 7 * (size_t)N + 256) * 4);  // padded rows + overread slack
    // ebuf aliases hsbA: ebuf uses [0, E*4); hsbA rows 0..N-1 use the same
    // range (E==32N), row N sits just past it. ebuf is dead after k_bfill.
    unsigned* hsbA    = (unsigned*)carve(((size_t)N + 1) * 32 * 4);
    unsigned* ebuf    = hsbA;
    unsigned* h1b     = (unsigned*)carve(((size_t)N + 1) * 32 * 4);  // bf16x2 relu'd h1
    unsigned* hsbB    = (unsigned*)carve(((size_t)N + 1) * 32 * 4);  // bf16x2 hs layer2
    float2*   zbuf    = (float2*)carve((size_t)N * 8);               // per-node head output

    const int chunk = (E + SGRID - 1) / SGRID;  // edges per block
    int wbl = (N + 3) / 4;                      // 4 waves (nodes) per 256-thread block
    int gbl = (N + 63) / 64;                    // 64 nodes per MFMA-gemm block

    k_bcount<<<SGRID, 1024, 0, stream>>>(dstp, blkhist, E, npb, chunk);
    k_bscan2<<<NB, SGRID, 0, stream>>>(blkhist, bcnt);
    k_bscan<<<1, NB, 0, stream>>>(bcnt, bstart);
    k_bscatter<<<SGRID, 1024, 0, stream>>>(srcp, dstp, bstart, blkhist, ebuf, E, npb, chunk);
    k_bfill<<<NB, 1024, 0, stream>>>(ebuf, bstart, rsA, cnt8, dinv, csr, N, npb);
    k_prep<<<1, 1024, 0, stream>>>(W1, W2, W1s, W2s, hsbA, hsbB, N);  // after bfill: hsbA aliases ebuf

    k_mgemm1<<<gbl, 256, 0, stream>>>(x, W1s, dinv, hsbA, N);
    k_conv1<<<wbl, 256, 0, stream>>>(hsbA, rsA, cnt8, csr, dinv, b1, h1b, N);
    k_mgemm2<<<gbl, 256, 0, stream>>>(h1b, W2s, dinv, hsbB, N);
    k_conv_out<<<wbl, 256, 0, stream>>>(hsbB, rsA, cnt8, csr, dinv, b2, Wl, zbuf, N);

    k_pool_z<<<(B * 64 + 255) / 256, 256, 0, stream>>>(zbuf, batch, bl, out, N, B);
}